// Round 13
// baseline (181.461 us; speedup 1.0000x reference)
//
#include <hip/hip_runtime.h>

#define VN 50000
#define EN 800000
#define CAP 48
#define USH 392           // U plane row stride in ushorts (16B-aligned)
#define LREC 12           // Ledge record stride in floats (3 mod 8 quads: conflict-free)
#define NBK 196           // buckets: bucket = tgt >> 8 (256 nodes each)
// cell path (r13):
#define CBLK 98           // pass-A blocks; 98*8192 = 802816 >= EN
#define CEPB 8192         // edges per pass-A block (512 thr x 16)
#define CCAP 88           // per-(block,bucket) cell capacity (+7 sigma of Bin(8192,0.00512))
// r8 fallback path:
#define BCAP 5120         // per-bucket capacity
#define AEPB 4096         // r8 pass A: edges per block

typedef short short8 __attribute__((ext_vector_type(8)));
typedef float float4v __attribute__((ext_vector_type(4)));

// ws layout in float units
#define WS_GBF   0        // f32[128] gamma ++ beta
#define WS_WHI   128      // ushort[24576] W_full hi, MFMA-B swizzled (K=384)
#define WS_WLO   12416    // ushort[24576] W_full lo
#define WS_POS   24704    // int[50000] per-node degree (written by pass B)
#define WS_REC   74704    // uint4[50000*48] {src,aphi,tphi,0}
// cell path:
#define WS_CNT   9674704                    // int[NBK*CBLK] cell counts
#define WS_CELL  (WS_CNT + NBK * CBLK)      // uint4[NBK*CBLK*CCAP]
#define WS_CELL_BYTES ((size_t)(WS_CELL + (size_t)NBK * CBLK * CCAP * 4) * 4) // 65.8 MB
// r8 fallback path (aliases the same region):
#define WS_GCNT  9674704  // int[196] bucket fill counters (memset to 0)
#define WS_BKT   9674960  // uint4[196*5120] bucket records {src,aphi,tphi,tgt}
#define WS_BKT_BYTES ((size_t)(9674960 + (size_t)NBK * BCAP * 4) * 4)  // 54.8 MB
#define WS_A_BYTES ((size_t)(74704 + 50000 * 48 * 4) * 4)              // 38.7 MB

// ledger: r1 nontemporal hints: +24us — never again.
//         r3 ph1 pair-load restructure: gem 86->95 despite -17% VALUBusy.
//         r4 prefetch depth 2->3: neutral. r5 4B-id records: gem +9us.
//         r6 64B-padded node cursors: neutral. r7 8 atomics in flight: neutral.
//         r8 WIN (-21us, 176.7): bucketed placement, 800K->38K glb atomics.
//         r9 FAIL: cooperative grid.sync ~75us each — never fine-fuse.
//         r10 occupancy doubling: neutral. r11: gem == L2-fill-bytes/1.2TB/s
//           (x-gather ~75MB random => gem floor ~85us); csr+gap only ~12us.
//         r12 gcount pad + payload hoist: neutral. conv_bucket ~65us vs
//           ~15us identifiable work.
//         r13 probe (pre-committed): atomic-free cells — no global atomics,
//           no mid-barrier, no cross-block line sharing in the scatter, no
//           memset dispatch. If neutral: cost is dispatch-intrinsic -> r8 is
//           the practical floor.

__device__ __forceinline__ float bf2f(unsigned short u) {
    return __uint_as_float(((unsigned int)u) << 16);
}
__device__ __forceinline__ unsigned short f2bf(float f) {
    unsigned int x = __float_as_uint(f);
    return (unsigned short)((x + 0x7fffu + ((x >> 16) & 1u)) >> 16);  // RNE
}
__device__ __forceinline__ float ldf(const void* p, int isbf, size_t i) {
    return isbf ? bf2f(((const unsigned short*)p)[i]) : ((const float*)p)[i];
}

// per-block dtype detect from x's bit pattern
__device__ __forceinline__ int block_detect(const void* xv) {
    __shared__ int flg;
    if (threadIdx.x < 64) {
        unsigned short w = ((const unsigned short*)xv)[2 * threadIdx.x];
        int e = (w >> 7) & 0xFF;
        bool ok = (e >= 0x70 && e <= 0x85) || (w == 0);
        unsigned long long m = __ballot(ok);
        if (threadIdx.x == 0) flg = (__popcll(m) >= 40) ? 1 : 0;
    }
    __syncthreads();
    return flg;
}

// W_full[k][n] = (k<320) ? W_neigh[k>>6][n][k&63] : K_self[n][k-320]
__device__ __forceinline__ void convert_dev(int idx, const void* Ks,
                                            const void* Wn, const void* gma,
                                            const void* bta, float* ws, int isbf) {
    if (idx < 128) {
        const void* p = (idx < 64) ? gma : bta;
        ws[WS_GBF + idx] = ldf(p, isbf, idx & 63);
    } else {
        int m2 = idx - 128;               // < 24576
        int j = m2 & 7;
        int chunk = m2 >> 3;
        int slot = chunk >> 6;
        int ln = chunk & 63;
        int ks = slot >> 2, wv = slot & 3;
        int k = ks * 32 + ((ln >> 4) * 8) + j;
        int n = wv * 16 + (ln & 15);
        float wvl;
        if (k < 320) {
            int b = k >> 6, i = k & 63;
            wvl = ldf(Wn, isbf, (b * 64 + n) * 64 + i);
        } else {
            wvl = ldf(Ks, isbf, n * 64 + (k - 320));
        }
        unsigned short hi = f2bf(wvl);
        unsigned short lo = f2bf(wvl - bf2f(hi));
        ((unsigned short*)(ws + WS_WHI))[m2] = hi;
        ((unsigned short*)(ws + WS_WLO))[m2] = lo;
    }
}

// ---------------------------------------------------------------------------
// r13 Pass A: atomic-free cell bucketing. 98 blocks x 512 thr x 16 edges.
// Streaming: per edge, one LDS hist atomic gives the slot in this block's
// PRIVATE cell [bucket][block][CCAP] — no global atomics, no mid barrier,
// no line shared between blocks. Counts written unconditionally (no memset).
// ---------------------------------------------------------------------------
__global__ __launch_bounds__(512) void conv_cell(
    const void* xv, const int* __restrict__ eidx, const void* angv,
    const void* trpv, const void* Ks, const void* Wn, const void* gma,
    const void* bta, float* __restrict__ ws) {
    __shared__ int hist[NBK];
    const int isbf = block_detect(xv);
    const int tid = threadIdx.x;
    const int blk = blockIdx.x;
    const int gtid = blk * 512 + tid;
    if (gtid < 128 + 24576) convert_dev(gtid, Ks, Wn, gma, bta, ws, isbf);

    for (int i = tid; i < NBK; i += 512) hist[i] = 0;
    __syncthreads();

    uint4* cell = (uint4*)(ws + WS_CELL);
    const int base = blk * CEPB;
#pragma unroll 4
    for (int k = 0; k < 16; ++k) {
        int e = base + k * 512 + tid;
        if (e < EN) {
            int tgt = eidx[EN + e];
            int b = tgt >> 8;
            int slot = atomicAdd(&hist[b], 1);
            if (slot < CCAP) {
                uint4 r;
                r.x = (unsigned int)eidx[e];
                r.y = __float_as_uint(ldf(angv, isbf, e));
                r.z = __float_as_uint(ldf(trpv, isbf, e));
                r.w = (unsigned int)tgt;
                cell[((size_t)b * CBLK + blk) * CCAP + slot] = r;
            }
        }
    }
    __syncthreads();
    for (int i = tid; i < NBK; i += 512)
        ((int*)(ws + WS_CNT))[i * CBLK + blk] = min(hist[i], CCAP);
}

// ---------------------------------------------------------------------------
// r13 Pass B: one block per bucket; flatten the bucket's 98 cells (98*88
// slots, ~48% live), slot via LDS cursors, write r0-format REC + pos[].
// ---------------------------------------------------------------------------
__global__ __launch_bounds__(512) void conv_csr2(float* __restrict__ ws) {
    __shared__ int cur[256];
    __shared__ int cs[CBLK];
    const int b = blockIdx.x;
    const int tid = threadIdx.x;
    for (int i = tid; i < 256; i += 512) cur[i] = 0;
    if (tid < CBLK) cs[tid] = ((const int*)(ws + WS_CNT))[b * CBLK + tid];
    __syncthreads();
    const uint4* cell = (const uint4*)(ws + WS_CELL);
    const int total = CBLK * CCAP;
    for (int i = tid; i < total; i += 512) {
        int s = i / CCAP, j = i - s * CCAP;
        if (j < cs[s]) {
            uint4 r = cell[((size_t)b * CBLK + s) * CCAP + j];
            int v = (int)r.w;
            int slot = atomicAdd(&cur[v & 255], 1);
            if (slot < CAP) {
                r.w = 0u;
                ((uint4*)(ws + WS_REC))[(size_t)v * CAP + slot] = r;
            }
        }
    }
    __syncthreads();
    const int v0 = b << 8;
    for (int i = tid; i < 256; i += 512) {
        int v = v0 + i;
        if (v < VN) ((int*)(ws + WS_POS))[v] = cur[i];
    }
}

// ---------------------------------------------------------------------------
// r8 fallback pair (proven 176.7us) — used when ws < 65.8 MB.
// ---------------------------------------------------------------------------
__global__ __launch_bounds__(512) void conv_bucket(
    const void* xv, const int* __restrict__ eidx, const void* angv,
    const void* trpv, const void* Ks, const void* Wn, const void* gma,
    const void* bta, float* __restrict__ ws) {
    __shared__ int hist[NBK];
    __shared__ int gbase[NBK];
    const int isbf = block_detect(xv);
    const int gtid = blockIdx.x * 512 + threadIdx.x;
    if (gtid < 128 + 24576) convert_dev(gtid, Ks, Wn, gma, bta, ws, isbf);

    for (int i = threadIdx.x; i < NBK; i += 512) hist[i] = 0;
    __syncthreads();

    const int base = blockIdx.x * AEPB + threadIdx.x;
    int tg[8], lsl[8];
#pragma unroll
    for (int k = 0; k < 8; ++k) {
        int e = base + k * 512;
        if (e < EN) {
            tg[k] = eidx[EN + e];
            lsl[k] = atomicAdd(&hist[tg[k] >> 8], 1);
        } else {
            tg[k] = -1;
        }
    }
    __syncthreads();
    for (int i = threadIdx.x; i < NBK; i += 512)
        gbase[i] = hist[i] ? atomicAdd(&((int*)(ws + WS_GCNT))[i], hist[i]) : 0;
    __syncthreads();
#pragma unroll
    for (int k = 0; k < 8; ++k) {
        if (tg[k] >= 0) {
            int idx = gbase[tg[k] >> 8] + lsl[k];
            if (idx < BCAP) {
                int e = base + k * 512;
                uint4 r;
                r.x = (unsigned int)eidx[e];
                r.y = __float_as_uint(ldf(angv, isbf, e));
                r.z = __float_as_uint(ldf(trpv, isbf, e));
                r.w = (unsigned int)tg[k];
                ((uint4*)(ws + WS_BKT))[(size_t)(tg[k] >> 8) * BCAP + idx] = r;
            }
        }
    }
}

__global__ __launch_bounds__(512) void conv_csr(float* __restrict__ ws) {
    __shared__ int cur[256];
    const int b = blockIdx.x;
    const int n = min(((const int*)(ws + WS_GCNT))[b], BCAP);
    for (int i = threadIdx.x; i < 256; i += 512) cur[i] = 0;
    __syncthreads();
    for (int i = threadIdx.x; i < n; i += 512) {
        uint4 r = ((const uint4*)(ws + WS_BKT))[(size_t)b * BCAP + i];
        int v = (int)r.w;
        int slot = atomicAdd(&cur[v & 255], 1);
        if (slot < CAP) {
            r.w = 0u;
            ((uint4*)(ws + WS_REC))[(size_t)v * CAP + slot] = r;
        }
    }
    __syncthreads();
    const int v0 = b << 8;
    for (int i = threadIdx.x; i < 256; i += 512) {
        int v = v0 + i;
        if (v < VN) ((int*)(ws + WS_POS))[v] = cur[i];
    }
}

// ---------------------------------------------------------------------------
// Fallback conv (ws too small for buckets): r0-proven atomic placement.
// ---------------------------------------------------------------------------
template <bool PAY>
__global__ __launch_bounds__(512) void conv_place(
    const void* xv, const int* __restrict__ eidx, const void* angv,
    const void* trpv, const void* Ks, const void* Wn, const void* gma,
    const void* bta, float* __restrict__ ws) {
    const int isbf = block_detect(xv);
    int gtid = blockIdx.x * 512 + threadIdx.x;
    if (gtid < 128 + 24576) convert_dev(gtid, Ks, Wn, gma, bta, ws, isbf);
    if (gtid < EN) {
        int tgt = eidx[EN + gtid];
        int slot = atomicAdd(&((int*)(ws + WS_POS))[tgt], 1);
        if (slot < CAP) {
            if (PAY) {
                uint4 r;
                r.x = (unsigned int)eidx[gtid];
                r.y = __float_as_uint(ldf(angv, isbf, gtid));
                r.z = __float_as_uint(ldf(trpv, isbf, gtid));
                r.w = 0u;
                ((uint4*)(ws + WS_REC))[(size_t)tgt * CAP + slot] = r;
            } else {
                ((int*)(ws + WS_REC))[(size_t)tgt * CAP + slot] = gtid;
            }
        }
    }
}

// ---------------------------------------------------------------------------
// gem: 512 thr = 8 waves = 8 nodes/block (4 blocks/CU, 32 waves = wave cap).
// r0-exact (85.5us, FETCH 89MB, VALU 83% — reproduced 8x). DO NOT TOUCH.
// Time model (r11): dur ~= L2-fill bytes / 1.2 TB/s; fetch is ~13MB live
// records + ~75MB random x-gather (structural floor ~85us).
// ---------------------------------------------------------------------------
template <bool BF, bool PAY>
__device__ __forceinline__ void gem_body(
    const void* xv, const int* __restrict__ eidx, const void* angv,
    const void* trpv, const float* __restrict__ ws, void* __restrict__ outv,
    float* Ledge, unsigned short* Uhi, unsigned short* Ulo) {
    const int t = threadIdx.x;
    const int lane = t & 63;
    const int w = t >> 6;                   // 0..7 = node row
    const int v0 = blockIdx.x * 8;
    const int* pos = (const int*)(ws + WS_POS);
    float* Cst = Ledge;                     // alias: 2 planes of 16x68 floats

    // ---- ph0: trig, one thread per (node,slot); pads zeroed ---------------
    if (t < 8 * CAP) {
        int n = t / CAP, s = t - n * CAP;
        int dn = min(pos[v0 + n], CAP);
        float* L = &Ledge[t * LREC];
        if (s < dn) {
            unsigned int srcb;
            float aphi, tphi;
            if (PAY) {
                uint4 r = ((const uint4*)(ws + WS_REC))[(size_t)(v0 + n) * CAP + s];
                srcb = r.x;
                aphi = __uint_as_float(r.y);
                tphi = __uint_as_float(r.z);
            } else {
                int e = ((const int*)(ws + WS_REC))[(size_t)(v0 + n) * CAP + s];
                srcb = (unsigned int)eidx[e];
                aphi = BF ? bf2f(((const unsigned short*)angv)[e])
                          : ((const float*)angv)[e];
                tphi = BF ? bf2f(((const unsigned short*)trpv)[e])
                          : ((const float*)trpv)[e];
            }
            float st, ct, sa, ca;
            __sincosf(tphi, &st, &ct);
            __sincosf(aphi, &sa, &ca);
            *(float4v*)(L)     = (float4v){__uint_as_float(srcb), ca, sa,
                                           fmaf(ca, ca, -sa * sa)};
            *(float4v*)(L + 4) = (float4v){ct, st, fmaf(ct, ct, -st * st),
                                           2.f * ct * st};
        } else {
            *(float4v*)(L)     = (float4v){__uint_as_float((unsigned)(v0 + n)),
                                           0.f, 0.f, 0.f};
            *(float4v*)(L + 4) = (float4v){0.f, 0.f, 0.f, 0.f};
        }
    }
    __syncthreads();

    // ---- ph1: node v = v0 + w, depth-2 pipelined gathers ------------------
    const int v = v0 + w;
    const int d = min(pos[v], CAP);
    const int R = (d + 3) >> 2;             // rounds of 4 (pads make them full)
    const int g = (lane < 16) ? 0 : ((lane < 48) ? 1 : 2);
    const unsigned int smask = (lane & 1) ? 0u : 0x80000000u;
    float a0 = 0.f, a1 = 0.f, a2 = 0.f, a3 = 0.f, a4 = 0.f;

    const float* Lb = &Ledge[w * CAP * LREC];
    auto srcOf = [&](int j) { return __float_as_uint(Lb[j * LREC]); };
    auto loadx = [&](unsigned int s) -> float {
        if (BF) return bf2f(((const unsigned short*)xv)[(size_t)s * 64 + lane]);
        else    return ((const float*)xv)[(size_t)s * 64 + lane];
    };
    auto edge1 = [&](int j, float xg) {
        const float* L = &Lb[j * LREC];
        float4v sh = *(const float4v*)L;          // {src, ca, sa, c2a}
        float4v rt = *(const float4v*)(L + 4);    // {ct, st, c2t, s2t}
        float cl = (g == 0) ? 1.f : ((g == 1) ? rt[0] : rt[2]);
        float sl = (g == 0) ? 0.f : ((g == 1) ? rt[1] : rt[3]);
        float prt = __shfl_xor(xg, 1, 64);
        float tmp = __uint_as_float(__float_as_uint(sl * prt) ^ smask);
        float fq = fmaf(cl, xg, tmp);
        a0 += fq;
        a1 = fmaf(sh[1], fq, a1);
        a2 = fmaf(sh[2], fq, a2);
        a3 = fmaf(sh[3], fq, a3);
        a4 = fmaf(2.f * sh[1] * sh[2], fq, a4);
    };

    float y[4], z[4];
#pragma unroll
    for (int u = 0; u < 4; ++u) y[u] = (R > 0) ? loadx(srcOf(u)) : 0.f;
#pragma unroll
    for (int u = 0; u < 4; ++u) z[u] = (R > 1) ? loadx(srcOf(4 + u)) : 0.f;

    for (int b = 0; b < R; ++b) {
        float nx[4] = {0.f, 0.f, 0.f, 0.f};
        if (b + 2 < R) {
            int j8 = (b + 2) * 4;
#pragma unroll
            for (int u = 0; u < 4; ++u) nx[u] = loadx(srcOf(j8 + u));
        }
        int j0 = b * 4;
#pragma unroll
        for (int u = 0; u < 4; ++u)
            edge1(j0 + u, (j0 + u < d) ? y[u] : 0.f);
#pragma unroll
        for (int u = 0; u < 4; ++u) { y[u] = z[u]; z[u] = nx[u]; }
    }

    float xown = BF ? bf2f(((const unsigned short*)xv)[(size_t)v * 64 + lane])
                    : ((const float*)xv)[(size_t)v * 64 + lane];
    auto wrU = [&](int c, float val) {
        unsigned short h = f2bf(val);
        unsigned short l = f2bf(val - bf2f(h));
        Uhi[w * USH + c * 64 + lane] = h;
        Ulo[w * USH + c * 64 + lane] = l;
    };
    wrU(0, a0); wrU(1, a1); wrU(2, a2); wrU(3, a3); wrU(4, a4); wrU(5, xown);
    __syncthreads();

    // ---- ph2: all 8 waves; slab = w&3, K-half = w>>2 ----------------------
    const int mcol = lane & 15, q = lane >> 4;
    {
        const int slab = w & 3, kh = w >> 2;
        const int mrow = mcol & 7;          // rows 8-15 mirror 0-7 (discarded)
        const unsigned short* Whi = (const unsigned short*)(ws + WS_WHI);
        const unsigned short* Wlo = (const unsigned short*)(ws + WS_WLO);
        float4v acc = (float4v){0.f, 0.f, 0.f, 0.f};
#pragma unroll
        for (int kk = 0; kk < 6; ++kk) {
            const int ks = kh * 6 + kk;
            short8 ahi = *(const short8*)&Uhi[mrow * USH + ks * 32 + q * 8];
            short8 alo = *(const short8*)&Ulo[mrow * USH + ks * 32 + q * 8];
            short8 bhi = *(const short8*)(Whi + ((size_t)(ks * 4 + slab) * 64 + lane) * 8);
            short8 blo = *(const short8*)(Wlo + ((size_t)(ks * 4 + slab) * 64 + lane) * 8);
            acc = __builtin_amdgcn_mfma_f32_16x16x32_bf16(ahi, bhi, acc, 0, 0, 0);
            acc = __builtin_amdgcn_mfma_f32_16x16x32_bf16(alo, bhi, acc, 0, 0, 0);
            acc = __builtin_amdgcn_mfma_f32_16x16x32_bf16(ahi, blo, acc, 0, 0, 0);
        }
#pragma unroll
        for (int reg = 0; reg < 4; ++reg)
            Cst[kh * 1088 + (q * 4 + reg) * 68 + slab * 16 + mcol] = acc[reg];
    }
    __syncthreads();

    // ---- ph3: LN + gated nonlinearity + residual --------------------------
    const float* gbf = ws + WS_GBF;
    float s = Cst[w * 68 + lane] + Cst[1088 + w * 68 + lane];
    float s1 = s, s2v = s * s;
#pragma unroll
    for (int off = 32; off > 0; off >>= 1) {
        s1 += __shfl_xor(s1, off, 64);
        s2v += __shfl_xor(s2v, off, 64);
    }
    float mu = s1 * (1.f / 64.f);
    float var = s2v * (1.f / 64.f) - mu * mu;
    float h = (s - mu) * rsqrtf(var + 1e-5f) * gbf[lane] + gbf[64 + lane];

    float prt = __shfl_xor(h, 1, 64);
    float rlt;
    if (lane < 16) {
        rlt = fmaxf(h, 0.f);
    } else {
        float nrm = sqrtf(h * h + prt * prt);
        nrm = fmaxf(nrm, 1e-8f);
        float sp = (nrm > 20.f) ? nrm : log1pf(__expf(nrm));
        rlt = h * (sp / nrm);
    }
    float xr = bf2f(Uhi[w * USH + 320 + lane]) + bf2f(Ulo[w * USH + 320 + lane]);
    float res = rlt + xr;
    if (BF) ((unsigned short*)outv)[(size_t)v * 64 + lane] = f2bf(res);
    else    ((float*)outv)[(size_t)v * 64 + lane] = res;
}

template <bool PAY>
__global__ __launch_bounds__(512, 8) void gem_kernel(
    const void* xv, const int* __restrict__ eidx, const void* angv,
    const void* trpv, const float* __restrict__ ws, void* __restrict__ outv) {
    // LDS shared between BF instantiations (~31 KB total -> 4 blocks/CU)
    __shared__ float Ledge[8 * CAP * LREC];      // 18.4 KB (ph2/3: Cst alias)
    __shared__ unsigned short Uhi[8 * USH];      // 6.3 KB
    __shared__ unsigned short Ulo[8 * USH];      // 6.3 KB

    const int isbf = block_detect(xv);
    if (isbf) gem_body<true, PAY>(xv, eidx, angv, trpv, ws, outv, Ledge, Uhi, Ulo);
    else      gem_body<false, PAY>(xv, eidx, angv, trpv, ws, outv, Ledge, Uhi, Ulo);
}

extern "C" void kernel_launch(void* const* d_in, const int* in_sizes, int n_in,
                              void* d_out, int out_size, void* d_ws, size_t ws_size,
                              hipStream_t stream) {
    const void* x   = d_in[0];
    const int* eidx = (const int*)d_in[1];
    const void* ang = d_in[2];
    const void* trp = d_in[3];
    const void* Ks  = d_in[4];
    const void* Wn  = d_in[5];
    const void* gma = d_in[6];
    const void* bta = d_in[7];
    float* ws = (float*)d_ws;

    if (ws_size >= WS_CELL_BYTES) {
        // r13 cell path: 3 dispatches, no memset, no global atomics
        conv_cell<<<CBLK, 512, 0, stream>>>(x, eidx, ang, trp, Ks, Wn,
                                            gma, bta, ws);
        conv_csr2<<<NBK, 512, 0, stream>>>(ws);
        gem_kernel<true><<<VN / 8, 512, 0, stream>>>(x, eidx, ang, trp, ws,
                                                     d_out);
    } else if (ws_size >= WS_BKT_BYTES) {
        hipMemsetAsync(ws + WS_GCNT, 0, NBK * sizeof(int), stream);
        const int nA = (EN + AEPB - 1) / AEPB;   // 196 blocks
        conv_bucket<<<nA, 512, 0, stream>>>(x, eidx, ang, trp, Ks, Wn,
                                            gma, bta, ws);
        conv_csr<<<NBK, 512, 0, stream>>>(ws);
        gem_kernel<true><<<VN / 8, 512, 0, stream>>>(x, eidx, ang, trp, ws,
                                                     d_out);
    } else if (ws_size >= WS_A_BYTES) {
        hipMemsetAsync(ws + WS_POS, 0, VN * sizeof(int), stream);
        conv_place<true><<<1563, 512, 0, stream>>>(x, eidx, ang, trp, Ks, Wn,
                                                   gma, bta, ws);
        gem_kernel<true><<<VN / 8, 512, 0, stream>>>(x, eidx, ang, trp, ws,
                                                     d_out);
    } else {
        hipMemsetAsync(ws + WS_POS, 0, VN * sizeof(int), stream);
        conv_place<false><<<1563, 512, 0, stream>>>(x, eidx, ang, trp, Ks, Wn,
                                                    gma, bta, ws);
        gem_kernel<false><<<VN / 8, 512, 0, stream>>>(x, eidx, ang, trp, ws,
                                                      d_out);
    }
}

// Round 14
// 176.619 us; speedup vs baseline: 1.0274x; 1.0274x over previous
//
#include <hip/hip_runtime.h>

#define VN 50000
#define EN 800000
#define CAP 48
#define USH 392           // U plane row stride in ushorts (16B-aligned)
#define LREC 12           // Ledge record stride in floats (3 mod 8 quads: conflict-free)
#define NBK 196           // buckets: bucket = tgt >> 8 (256 nodes each)
#define BCAP 5120         // per-bucket capacity (mean 4096, sd 63 -> +16 sd)
#define EPB 4096          // pass A: edges per block (512 thr x 8 edges)

typedef short short8 __attribute__((ext_vector_type(8)));
typedef float float4v __attribute__((ext_vector_type(4)));

// ws layout in float units
#define WS_GBF   0        // f32[128] gamma ++ beta
#define WS_WHI   128      // ushort[24576] W_full hi, MFMA-B swizzled (K=384)
#define WS_WLO   12416    // ushort[24576] W_full lo
#define WS_POS   24704    // int[50000] per-node degree (written by pass B)
#define WS_REC   74704    // uint4[50000*48] {src,aphi,tphi,0}
#define WS_GCNT  9674704  // int[196] bucket fill counters (memset to 0)
#define WS_BKT   9674960  // uint4[196*5120] bucket records {src,aphi,tphi,tgt}
#define WS_BKT_BYTES ((size_t)(9674960 + (size_t)NBK * BCAP * 4) * 4)  // 54.8 MB
#define WS_A_BYTES ((size_t)(74704 + 50000 * 48 * 4) * 4)              // 38.7 MB

// FINAL CONFIGURATION (r8-exact, best measured: 176.7us total).
// Floor model: gem = 89MB L2-fill / 1.2TB/s = ~85us (9x reproduced);
// conv = bucketize+csr ~85-90us, invariant under removal of every
// identifiable mechanism. Refutation ledger:
//   r1 nontemporal hints: +24us (records evicted from L3).
//   r3 ph1 pair-load restructure: gem 86->95 despite -17% VALUBusy
//     (random-line service rate governs, not VALU count).
//   r4 prefetch depth 2->3: neutral (not latency-depth-bound).
//   r5 4B-id records: gem +9us (random re-gather); conv unchanged
//     (not store-payload-bound).
//   r6 64B-padded node cursors: neutral (not line-contention-bound).
//   r7 8 atomics in flight/lane: neutral (not atomic-latency-bound).
//   r8 WIN -21us: 800K->38K global atomics (atomic-COUNT was real).
//   r9 cooperative grid.sync: ~75us each on this runtime — never fine-fuse.
//   r10 occupancy doubling both passes: neutral (not wave-bound).
//   r11 gem-side bucket scan: +14us (re-read amplification); proved
//     csr+gap ~12us, conv_bucket ~65us, gem fetch mostly x-gather.
//   r12 gcount 64B-pad + payload hoist: neutral.
//   r13 atomic-free private cells (no glb atomics, no barrier, no line
//     sharing, no memset): neutral => conv cost is structural.

__device__ __forceinline__ float bf2f(unsigned short u) {
    return __uint_as_float(((unsigned int)u) << 16);
}
__device__ __forceinline__ unsigned short f2bf(float f) {
    unsigned int x = __float_as_uint(f);
    return (unsigned short)((x + 0x7fffu + ((x >> 16) & 1u)) >> 16);  // RNE
}
__device__ __forceinline__ float ldf(const void* p, int isbf, size_t i) {
    return isbf ? bf2f(((const unsigned short*)p)[i]) : ((const float*)p)[i];
}

// per-block dtype detect from x's bit pattern
__device__ __forceinline__ int block_detect(const void* xv) {
    __shared__ int flg;
    if (threadIdx.x < 64) {
        unsigned short w = ((const unsigned short*)xv)[2 * threadIdx.x];
        int e = (w >> 7) & 0xFF;
        bool ok = (e >= 0x70 && e <= 0x85) || (w == 0);
        unsigned long long m = __ballot(ok);
        if (threadIdx.x == 0) flg = (__popcll(m) >= 40) ? 1 : 0;
    }
    __syncthreads();
    return flg;
}

// W_full[k][n] = (k<320) ? W_neigh[k>>6][n][k&63] : K_self[n][k-320]
__device__ __forceinline__ void convert_dev(int idx, const void* Ks,
                                            const void* Wn, const void* gma,
                                            const void* bta, float* ws, int isbf) {
    if (idx < 128) {
        const void* p = (idx < 64) ? gma : bta;
        ws[WS_GBF + idx] = ldf(p, isbf, idx & 63);
    } else {
        int m2 = idx - 128;               // < 24576
        int j = m2 & 7;
        int chunk = m2 >> 3;
        int slot = chunk >> 6;
        int ln = chunk & 63;
        int ks = slot >> 2, wv = slot & 3;
        int k = ks * 32 + ((ln >> 4) * 8) + j;
        int n = wv * 16 + (ln & 15);
        float wvl;
        if (k < 320) {
            int b = k >> 6, i = k & 63;
            wvl = ldf(Wn, isbf, (b * 64 + n) * 64 + i);
        } else {
            wvl = ldf(Ks, isbf, n * 64 + (k - 320));
        }
        unsigned short hi = f2bf(wvl);
        unsigned short lo = f2bf(wvl - bf2f(hi));
        ((unsigned short*)(ws + WS_WHI))[m2] = hi;
        ((unsigned short*)(ws + WS_WLO))[m2] = lo;
    }
}

// ---------------------------------------------------------------------------
// Pass A: weight canonicalization + coarse bucketing.
// LDS histogram over 196 buckets gives each edge a local slot (LDS atomic);
// ONE global atomic per (block,bucket) reserves the bucket base: ~38K global
// atomics total vs 800K.
// ---------------------------------------------------------------------------
__global__ __launch_bounds__(512) void conv_bucket(
    const void* xv, const int* __restrict__ eidx, const void* angv,
    const void* trpv, const void* Ks, const void* Wn, const void* gma,
    const void* bta, float* __restrict__ ws) {
    __shared__ int hist[NBK];
    __shared__ int gbase[NBK];
    const int isbf = block_detect(xv);
    const int gtid = blockIdx.x * 512 + threadIdx.x;
    if (gtid < 128 + 24576) convert_dev(gtid, Ks, Wn, gma, bta, ws, isbf);

    for (int i = threadIdx.x; i < NBK; i += 512) hist[i] = 0;
    __syncthreads();

    const int base = blockIdx.x * EPB + threadIdx.x;
    int tg[8], lsl[8];
#pragma unroll
    for (int k = 0; k < 8; ++k) {
        int e = base + k * 512;
        if (e < EN) {
            tg[k] = eidx[EN + e];
            lsl[k] = atomicAdd(&hist[tg[k] >> 8], 1);
        } else {
            tg[k] = -1;
        }
    }
    __syncthreads();
    for (int i = threadIdx.x; i < NBK; i += 512)
        gbase[i] = hist[i] ? atomicAdd(&((int*)(ws + WS_GCNT))[i], hist[i]) : 0;
    __syncthreads();
#pragma unroll
    for (int k = 0; k < 8; ++k) {
        if (tg[k] >= 0) {
            int idx = gbase[tg[k] >> 8] + lsl[k];
            if (idx < BCAP) {
                int e = base + k * 512;
                uint4 r;
                r.x = (unsigned int)eidx[e];
                r.y = __float_as_uint(ldf(angv, isbf, e));
                r.z = __float_as_uint(ldf(trpv, isbf, e));
                r.w = (unsigned int)tg[k];
                ((uint4*)(ws + WS_BKT))[(size_t)(tg[k] >> 8) * BCAP + idx] = r;
            }
        }
    }
}

// ---------------------------------------------------------------------------
// Pass B: one block per bucket. Stream bucket records (coalesced), slot via
// LDS cursors (256 nodes), write r0-format CSR records into a 196KB
// L2-resident window. Writes pos[] (degree) — no pos memset needed.
// ---------------------------------------------------------------------------
__global__ __launch_bounds__(512) void conv_csr(float* __restrict__ ws) {
    __shared__ int cur[256];
    const int b = blockIdx.x;
    const int n = min(((const int*)(ws + WS_GCNT))[b], BCAP);
    for (int i = threadIdx.x; i < 256; i += 512) cur[i] = 0;
    __syncthreads();
    for (int i = threadIdx.x; i < n; i += 512) {
        uint4 r = ((const uint4*)(ws + WS_BKT))[(size_t)b * BCAP + i];
        int v = (int)r.w;
        int slot = atomicAdd(&cur[v & 255], 1);
        if (slot < CAP) {
            r.w = 0u;
            ((uint4*)(ws + WS_REC))[(size_t)v * CAP + slot] = r;
        }
    }
    __syncthreads();
    const int v0 = b << 8;
    for (int i = threadIdx.x; i < 256; i += 512) {
        int v = v0 + i;
        if (v < VN) ((int*)(ws + WS_POS))[v] = cur[i];
    }
}

// ---------------------------------------------------------------------------
// Fallback conv (ws too small for buckets): r0-proven atomic placement.
// ---------------------------------------------------------------------------
template <bool PAY>
__global__ __launch_bounds__(512) void conv_place(
    const void* xv, const int* __restrict__ eidx, const void* angv,
    const void* trpv, const void* Ks, const void* Wn, const void* gma,
    const void* bta, float* __restrict__ ws) {
    const int isbf = block_detect(xv);
    int gtid = blockIdx.x * 512 + threadIdx.x;
    if (gtid < 128 + 24576) convert_dev(gtid, Ks, Wn, gma, bta, ws, isbf);
    if (gtid < EN) {
        int tgt = eidx[EN + gtid];
        int slot = atomicAdd(&((int*)(ws + WS_POS))[tgt], 1);
        if (slot < CAP) {
            if (PAY) {
                uint4 r;
                r.x = (unsigned int)eidx[gtid];
                r.y = __float_as_uint(ldf(angv, isbf, gtid));
                r.z = __float_as_uint(ldf(trpv, isbf, gtid));
                r.w = 0u;
                ((uint4*)(ws + WS_REC))[(size_t)tgt * CAP + slot] = r;
            } else {
                ((int*)(ws + WS_REC))[(size_t)tgt * CAP + slot] = gtid;
            }
        }
    }
}

// ---------------------------------------------------------------------------
// gem: 512 thr = 8 waves = 8 nodes/block (4 blocks/CU, 32 waves = wave cap).
// r0-exact (85.5us, FETCH 89MB, VALU 83% — reproduced 9x). DO NOT TOUCH.
//  ph0: per-edge trig -> 12-float records {src,ca,sa,c2a | ct,st,c2t,s2t}
//  ph1: node per wave; depth-2 pipelined gathers.
//  ph2: all 8 waves: slab = w&3, K-half = w>>2; partial C planes.
//  ph3: LN + gated nonlinearity + residual.
// ---------------------------------------------------------------------------
template <bool BF, bool PAY>
__device__ __forceinline__ void gem_body(
    const void* xv, const int* __restrict__ eidx, const void* angv,
    const void* trpv, const float* __restrict__ ws, void* __restrict__ outv,
    float* Ledge, unsigned short* Uhi, unsigned short* Ulo) {
    const int t = threadIdx.x;
    const int lane = t & 63;
    const int w = t >> 6;                   // 0..7 = node row
    const int v0 = blockIdx.x * 8;
    const int* pos = (const int*)(ws + WS_POS);
    float* Cst = Ledge;                     // alias: 2 planes of 16x68 floats

    // ---- ph0: trig, one thread per (node,slot); pads zeroed ---------------
    if (t < 8 * CAP) {
        int n = t / CAP, s = t - n * CAP;
        int dn = min(pos[v0 + n], CAP);
        float* L = &Ledge[t * LREC];
        if (s < dn) {
            unsigned int srcb;
            float aphi, tphi;
            if (PAY) {
                uint4 r = ((const uint4*)(ws + WS_REC))[(size_t)(v0 + n) * CAP + s];
                srcb = r.x;
                aphi = __uint_as_float(r.y);
                tphi = __uint_as_float(r.z);
            } else {
                int e = ((const int*)(ws + WS_REC))[(size_t)(v0 + n) * CAP + s];
                srcb = (unsigned int)eidx[e];
                aphi = BF ? bf2f(((const unsigned short*)angv)[e])
                          : ((const float*)angv)[e];
                tphi = BF ? bf2f(((const unsigned short*)trpv)[e])
                          : ((const float*)trpv)[e];
            }
            float st, ct, sa, ca;
            __sincosf(tphi, &st, &ct);
            __sincosf(aphi, &sa, &ca);
            *(float4v*)(L)     = (float4v){__uint_as_float(srcb), ca, sa,
                                           fmaf(ca, ca, -sa * sa)};
            *(float4v*)(L + 4) = (float4v){ct, st, fmaf(ct, ct, -st * st),
                                           2.f * ct * st};
        } else {
            *(float4v*)(L)     = (float4v){__uint_as_float((unsigned)(v0 + n)),
                                           0.f, 0.f, 0.f};
            *(float4v*)(L + 4) = (float4v){0.f, 0.f, 0.f, 0.f};
        }
    }
    __syncthreads();

    // ---- ph1: node v = v0 + w, depth-2 pipelined gathers ------------------
    const int v = v0 + w;
    const int d = min(pos[v], CAP);
    const int R = (d + 3) >> 2;             // rounds of 4 (pads make them full)
    const int g = (lane < 16) ? 0 : ((lane < 48) ? 1 : 2);
    const unsigned int smask = (lane & 1) ? 0u : 0x80000000u;
    float a0 = 0.f, a1 = 0.f, a2 = 0.f, a3 = 0.f, a4 = 0.f;

    const float* Lb = &Ledge[w * CAP * LREC];
    auto srcOf = [&](int j) { return __float_as_uint(Lb[j * LREC]); };
    auto loadx = [&](unsigned int s) -> float {
        if (BF) return bf2f(((const unsigned short*)xv)[(size_t)s * 64 + lane]);
        else    return ((const float*)xv)[(size_t)s * 64 + lane];
    };
    auto edge1 = [&](int j, float xg) {
        const float* L = &Lb[j * LREC];
        float4v sh = *(const float4v*)L;          // {src, ca, sa, c2a}
        float4v rt = *(const float4v*)(L + 4);    // {ct, st, c2t, s2t}
        float cl = (g == 0) ? 1.f : ((g == 1) ? rt[0] : rt[2]);
        float sl = (g == 0) ? 0.f : ((g == 1) ? rt[1] : rt[3]);
        float prt = __shfl_xor(xg, 1, 64);
        float tmp = __uint_as_float(__float_as_uint(sl * prt) ^ smask);
        float fq = fmaf(cl, xg, tmp);
        a0 += fq;
        a1 = fmaf(sh[1], fq, a1);
        a2 = fmaf(sh[2], fq, a2);
        a3 = fmaf(sh[3], fq, a3);
        a4 = fmaf(2.f * sh[1] * sh[2], fq, a4);
    };

    float y[4], z[4];
#pragma unroll
    for (int u = 0; u < 4; ++u) y[u] = (R > 0) ? loadx(srcOf(u)) : 0.f;
#pragma unroll
    for (int u = 0; u < 4; ++u) z[u] = (R > 1) ? loadx(srcOf(4 + u)) : 0.f;

    for (int b = 0; b < R; ++b) {
        float nx[4] = {0.f, 0.f, 0.f, 0.f};
        if (b + 2 < R) {
            int j8 = (b + 2) * 4;
#pragma unroll
            for (int u = 0; u < 4; ++u) nx[u] = loadx(srcOf(j8 + u));
        }
        int j0 = b * 4;
#pragma unroll
        for (int u = 0; u < 4; ++u)
            edge1(j0 + u, (j0 + u < d) ? y[u] : 0.f);
#pragma unroll
        for (int u = 0; u < 4; ++u) { y[u] = z[u]; z[u] = nx[u]; }
    }

    float xown = BF ? bf2f(((const unsigned short*)xv)[(size_t)v * 64 + lane])
                    : ((const float*)xv)[(size_t)v * 64 + lane];
    auto wrU = [&](int c, float val) {
        unsigned short h = f2bf(val);
        unsigned short l = f2bf(val - bf2f(h));
        Uhi[w * USH + c * 64 + lane] = h;
        Ulo[w * USH + c * 64 + lane] = l;
    };
    wrU(0, a0); wrU(1, a1); wrU(2, a2); wrU(3, a3); wrU(4, a4); wrU(5, xown);
    __syncthreads();

    // ---- ph2: all 8 waves; slab = w&3, K-half = w>>2 ----------------------
    const int mcol = lane & 15, q = lane >> 4;
    {
        const int slab = w & 3, kh = w >> 2;
        const int mrow = mcol & 7;          // rows 8-15 mirror 0-7 (discarded)
        const unsigned short* Whi = (const unsigned short*)(ws + WS_WHI);
        const unsigned short* Wlo = (const unsigned short*)(ws + WS_WLO);
        float4v acc = (float4v){0.f, 0.f, 0.f, 0.f};
#pragma unroll
        for (int kk = 0; kk < 6; ++kk) {
            const int ks = kh * 6 + kk;
            short8 ahi = *(const short8*)&Uhi[mrow * USH + ks * 32 + q * 8];
            short8 alo = *(const short8*)&Ulo[mrow * USH + ks * 32 + q * 8];
            short8 bhi = *(const short8*)(Whi + ((size_t)(ks * 4 + slab) * 64 + lane) * 8);
            short8 blo = *(const short8*)(Wlo + ((size_t)(ks * 4 + slab) * 64 + lane) * 8);
            acc = __builtin_amdgcn_mfma_f32_16x16x32_bf16(ahi, bhi, acc, 0, 0, 0);
            acc = __builtin_amdgcn_mfma_f32_16x16x32_bf16(alo, bhi, acc, 0, 0, 0);
            acc = __builtin_amdgcn_mfma_f32_16x16x32_bf16(ahi, blo, acc, 0, 0, 0);
        }
#pragma unroll
        for (int reg = 0; reg < 4; ++reg)
            Cst[kh * 1088 + (q * 4 + reg) * 68 + slab * 16 + mcol] = acc[reg];
    }
    __syncthreads();

    // ---- ph3: LN + gated nonlinearity + residual --------------------------
    const float* gbf = ws + WS_GBF;
    float s = Cst[w * 68 + lane] + Cst[1088 + w * 68 + lane];
    float s1 = s, s2v = s * s;
#pragma unroll
    for (int off = 32; off > 0; off >>= 1) {
        s1 += __shfl_xor(s1, off, 64);
        s2v += __shfl_xor(s2v, off, 64);
    }
    float mu = s1 * (1.f / 64.f);
    float var = s2v * (1.f / 64.f) - mu * mu;
    float h = (s - mu) * rsqrtf(var + 1e-5f) * gbf[lane] + gbf[64 + lane];

    float prt = __shfl_xor(h, 1, 64);
    float rlt;
    if (lane < 16) {
        rlt = fmaxf(h, 0.f);
    } else {
        float nrm = sqrtf(h * h + prt * prt);
        nrm = fmaxf(nrm, 1e-8f);
        float sp = (nrm > 20.f) ? nrm : log1pf(__expf(nrm));
        rlt = h * (sp / nrm);
    }
    float xr = bf2f(Uhi[w * USH + 320 + lane]) + bf2f(Ulo[w * USH + 320 + lane]);
    float res = rlt + xr;
    if (BF) ((unsigned short*)outv)[(size_t)v * 64 + lane] = f2bf(res);
    else    ((float*)outv)[(size_t)v * 64 + lane] = res;
}

template <bool PAY>
__global__ __launch_bounds__(512, 8) void gem_kernel(
    const void* xv, const int* __restrict__ eidx, const void* angv,
    const void* trpv, const float* __restrict__ ws, void* __restrict__ outv) {
    // LDS shared between BF instantiations (~31 KB total -> 4 blocks/CU)
    __shared__ float Ledge[8 * CAP * LREC];      // 18.4 KB (ph2/3: Cst alias)
    __shared__ unsigned short Uhi[8 * USH];      // 6.3 KB
    __shared__ unsigned short Ulo[8 * USH];      // 6.3 KB

    const int isbf = block_detect(xv);
    if (isbf) gem_body<true, PAY>(xv, eidx, angv, trpv, ws, outv, Ledge, Uhi, Ulo);
    else      gem_body<false, PAY>(xv, eidx, angv, trpv, ws, outv, Ledge, Uhi, Ulo);
}

extern "C" void kernel_launch(void* const* d_in, const int* in_sizes, int n_in,
                              void* d_out, int out_size, void* d_ws, size_t ws_size,
                              hipStream_t stream) {
    const void* x   = d_in[0];
    const int* eidx = (const int*)d_in[1];
    const void* ang = d_in[2];
    const void* trp = d_in[3];
    const void* Ks  = d_in[4];
    const void* Wn  = d_in[5];
    const void* gma = d_in[6];
    const void* bta = d_in[7];
    float* ws = (float*)d_ws;

    if (ws_size >= WS_BKT_BYTES) {
        // bucketed path: only the 196 bucket counters need zeroing
        hipMemsetAsync(ws + WS_GCNT, 0, NBK * sizeof(int), stream);
        const int nA = (EN + EPB - 1) / EPB;   // 196 blocks
        conv_bucket<<<nA, 512, 0, stream>>>(x, eidx, ang, trp, Ks, Wn,
                                            gma, bta, ws);
        conv_csr<<<NBK, 512, 0, stream>>>(ws);
        gem_kernel<true><<<VN / 8, 512, 0, stream>>>(x, eidx, ang, trp, ws,
                                                     d_out);
    } else if (ws_size >= WS_A_BYTES) {
        hipMemsetAsync(ws + WS_POS, 0, VN * sizeof(int), stream);
        conv_place<true><<<1563, 512, 0, stream>>>(x, eidx, ang, trp, Ks, Wn,
                                                   gma, bta, ws);
        gem_kernel<true><<<VN / 8, 512, 0, stream>>>(x, eidx, ang, trp, ws,
                                                     d_out);
    } else {
        hipMemsetAsync(ws + WS_POS, 0, VN * sizeof(int), stream);
        conv_place<false><<<1563, 512, 0, stream>>>(x, eidx, ang, trp, Ks, Wn,
                                                    gma, bta, ws);
        gem_kernel<false><<<VN / 8, 512, 0, stream>>>(x, eidx, ang, trp, ws,
                                                      d_out);
    }
}